// Round 1
// baseline (602.062 us; speedup 1.0000x reference)
//
#include <hip/hip_runtime.h>
#include <hip/hip_bf16.h>
#include <stdint.h>

// LightGCN on MI355X, round 4.
// R3 post-mortem: bucketed CSR build FAILED its goal — k_fill_part showed
// WRITE_SIZE=166MB (13x amplification, same as R2) + FETCH=101MB (8x edge
// streaming). blockIdx->XCD mapping is undefined, and device-scope atomics
// resolve at the memory-side cache anyway, so XCD-bucketing bought nothing.
// R4: single-pass count + single-pass fill; csrc scatter writes use
// agent-scope stores (bypass non-coherent per-XCD L2, combine in the
// coherent memory-side Infinity Cache -> full-line HBM writebacks only).
// SpMV unchanged from R3 (wave=dst node, 8 rows/wave-load, shfl reduce).

#define N_NODES 100000
#define N_EDGES 3200000
#define DIM 64

#define SCAN_BLOCK 256
#define SCAN_ITEMS 8
#define SCAN_CHUNK (SCAN_BLOCK * SCAN_ITEMS)  // 2048
#define SCAN_NBLOCKS ((N_NODES + SCAN_CHUNK - 1) / SCAN_CHUNK)  // 49

#define EDGE_VEC (N_EDGES / 4)  // 800000 int4 groups, exact

__device__ __forceinline__ float bl(unsigned u) { return __uint_as_float(u << 16); }
__device__ __forceinline__ float bh(unsigned u) { return __uint_as_float(u & 0xffff0000u); }

__device__ __forceinline__ void store_wt(int* p, int v) {
    // agent-scope relaxed store: writes through the (non-coherent) per-XCD L2
    // to the coherent memory-side cache, where partial lines combine.
    __hip_atomic_store(p, v, __ATOMIC_RELAXED, __HIP_MEMORY_SCOPE_AGENT);
}

// ---- single-pass degree count (reads col only: 12.8 MB) ----
__global__ __launch_bounds__(256) void k_count(const int* __restrict__ ei,
                                               int* __restrict__ deg) {
    int i = blockIdx.x * blockDim.x + threadIdx.x;
    if (i >= EDGE_VEC) return;
    const int4* col4 = (const int4*)(ei + N_EDGES);
    int4 c = col4[i];
    atomicAdd(&deg[c.x], 1);
    atomicAdd(&deg[c.y], 1);
    atomicAdd(&deg[c.z], 1);
    atomicAdd(&deg[c.w], 1);
}

__global__ void k_dinv(const int* __restrict__ deg, float* __restrict__ dinv) {
    int i = blockIdx.x * blockDim.x + threadIdx.x;
    if (i < N_NODES) {
        int d = deg[i];
        dinv[i] = (d > 0) ? rsqrtf((float)d) : 0.0f;
    }
}

// ---- exclusive scan of deg -> base ----
__global__ void k_scan1(const int* __restrict__ deg, int* __restrict__ base,
                        int* __restrict__ bsums) {
    int t = threadIdx.x;
    int idx0 = blockIdx.x * SCAN_CHUNK + t * SCAN_ITEMS;

    int v[SCAN_ITEMS];
    int s = 0;
#pragma unroll
    for (int k = 0; k < SCAN_ITEMS; k++) {
        int idx = idx0 + k;
        v[k] = (idx < N_NODES) ? deg[idx] : 0;
        s += v[k];
    }
    int lane = t & 63;
    int waveId = t >> 6;
    int sum = s;
#pragma unroll
    for (int off = 1; off < 64; off <<= 1) {
        int u = __shfl_up(sum, off);
        if (lane >= off) sum += u;
    }
    int exclusive = sum - s;

    __shared__ int waveTotals[4];
    if (lane == 63) waveTotals[waveId] = sum;
    __syncthreads();
    int waveOff = 0;
    for (int w = 0; w < waveId; w++) waveOff += waveTotals[w];

    int run = exclusive + waveOff;
#pragma unroll
    for (int k = 0; k < SCAN_ITEMS; k++) {
        int idx = idx0 + k;
        if (idx < N_NODES) base[idx] = run;
        run += v[k];
    }
    if (t == SCAN_BLOCK - 1) bsums[blockIdx.x] = run;
}

__global__ void k_scan2(int* __restrict__ bsums, int numBlocks) {
    int lane = threadIdx.x;
    int v = (lane < numBlocks) ? bsums[lane] : 0;
    int sum = v;
#pragma unroll
    for (int off = 1; off < 64; off <<= 1) {
        int u = __shfl_up(sum, off);
        if (lane >= off) sum += u;
    }
    if (lane < numBlocks) bsums[lane] = sum - v;
}

__global__ void k_scan3(int* __restrict__ base, const int* __restrict__ bsums,
                        int* __restrict__ cursor) {
    int i = blockIdx.x * blockDim.x + threadIdx.x;
    if (i < N_NODES) {
        int b = base[i] + bsums[i / SCAN_CHUNK];
        base[i] = b;
        cursor[i] = b;
    }
}

// ---- single-pass CSR fill: 4 atomics issued back-to-back (MLP), then
// 4 agent-scope scatter stores ----
__global__ __launch_bounds__(256) void k_fill(const int* __restrict__ ei,
                                              int* __restrict__ cursor,
                                              int* __restrict__ csrc) {
    int i = blockIdx.x * blockDim.x + threadIdx.x;
    if (i >= EDGE_VEC) return;
    const int4* row4 = (const int4*)ei;
    const int4* col4 = (const int4*)(ei + N_EDGES);
    int4 c = col4[i];
    int4 r = row4[i];
    int p0 = atomicAdd(&cursor[c.x], 1);
    int p1 = atomicAdd(&cursor[c.y], 1);
    int p2 = atomicAdd(&cursor[c.z], 1);
    int p3 = atomicAdd(&cursor[c.w], 1);
    store_wt(&csrc[p0], r.x);
    store_wt(&csrc[p1], r.y);
    store_wt(&csrc[p2], r.z);
    store_wt(&csrc[p3], r.w);
}

// z0 = bf16(emb * dinv[node]) ; vectorized 4 elems/thread
__global__ void k_z0(const float* __restrict__ emb, const float* __restrict__ dinv,
                     __hip_bfloat16* __restrict__ z) {
    int i = blockIdx.x * blockDim.x + threadIdx.x;  // group of 4 elements
    if (i >= (N_NODES * DIM) / 4) return;
    float di = dinv[(i * 4) >> 6];
    const float4 v = ((const float4*)emb)[i];
    union { ushort h[4]; uint2 u; } pk;
    __hip_bfloat16 b0 = __float2bfloat16(v.x * di);
    __hip_bfloat16 b1 = __float2bfloat16(v.y * di);
    __hip_bfloat16 b2 = __float2bfloat16(v.z * di);
    __hip_bfloat16 b3 = __float2bfloat16(v.w * di);
    pk.h[0] = *(ushort*)&b0; pk.h[1] = *(ushort*)&b1;
    pk.h[2] = *(ushort*)&b2; pk.h[3] = *(ushort*)&b3;
    ((uint2*)z)[i] = pk.u;
}

// ---- SpMV: one wave per dst node; 8 rows gathered per wave-load ----
// mode 0: acc = emb + xo; znext = bf16(xo*dinv)
// mode 1: acc += xo;      znext = bf16(xo*dinv)
// mode 2: acc = (acc + xo) * 0.25
__global__ __launch_bounds__(256) void k_spmv(
    const int* __restrict__ base, const int* __restrict__ deg,
    const int* __restrict__ csrc, const __hip_bfloat16* __restrict__ z,
    const float* __restrict__ dinv, __hip_bfloat16* __restrict__ znext,
    const float* __restrict__ emb, float* __restrict__ acc_out, int mode) {
    int wave = (blockIdx.x * blockDim.x + threadIdx.x) >> 6;
    int lane = threadIdx.x & 63;
    if (wave >= N_NODES) return;
    int g = lane >> 3;   // edge slot 0..7
    int l = lane & 7;    // feature chunk: features [l*8, l*8+8)

    int start = base[wave];
    int cnt = deg[wave];

    float acc[8] = {0, 0, 0, 0, 0, 0, 0, 0};

#define ACCUM(U)                                   \
    do {                                           \
        acc[0] += bl((U).x); acc[1] += bh((U).x);  \
        acc[2] += bl((U).y); acc[3] += bh((U).y);  \
        acc[4] += bl((U).z); acc[5] += bh((U).z);  \
        acc[6] += bl((U).w); acc[7] += bh((U).w);  \
    } while (0)

    int pos = 0;
    for (; pos + 32 <= cnt; pos += 32) {
        int i0 = start + pos + g;
        int s0 = csrc[i0];
        int s1 = csrc[i0 + 8];
        int s2 = csrc[i0 + 16];
        int s3 = csrc[i0 + 24];
        uint4 v0 = *((const uint4*)(z + ((size_t)s0 << 6)) + l);
        uint4 v1 = *((const uint4*)(z + ((size_t)s1 << 6)) + l);
        uint4 v2 = *((const uint4*)(z + ((size_t)s2 << 6)) + l);
        uint4 v3 = *((const uint4*)(z + ((size_t)s3 << 6)) + l);
        ACCUM(v0); ACCUM(v1); ACCUM(v2); ACCUM(v3);
    }
    for (; pos < cnt; pos += 8) {
        int idx = pos + g;
        if (idx < cnt) {
            int s = csrc[start + idx];
            uint4 v = *((const uint4*)(z + ((size_t)s << 6)) + l);
            ACCUM(v);
        }
    }
#undef ACCUM

    // reduce across the 8 edge-slot groups (lane bits 3,4,5)
#pragma unroll
    for (int j = 0; j < 8; j++) {
        acc[j] += __shfl_xor(acc[j], 8);
        acc[j] += __shfl_xor(acc[j], 16);
        acc[j] += __shfl_xor(acc[j], 32);
    }

    if (lane < 8) {  // lane == l, holds features [l*8, l*8+8)
        float di = dinv[wave];
        size_t o = (size_t)wave * DIM + lane * 8;
        float xo[8];
#pragma unroll
        for (int j = 0; j < 8; j++) xo[j] = acc[j] * di;

        float4 o0, o1;
        if (mode == 0) {
            float4 e0 = ((const float4*)(emb + o))[0];
            float4 e1 = ((const float4*)(emb + o))[1];
            o0 = make_float4(e0.x + xo[0], e0.y + xo[1], e0.z + xo[2], e0.w + xo[3]);
            o1 = make_float4(e1.x + xo[4], e1.y + xo[5], e1.z + xo[6], e1.w + xo[7]);
        } else if (mode == 1) {
            float4 a0 = ((const float4*)(acc_out + o))[0];
            float4 a1 = ((const float4*)(acc_out + o))[1];
            o0 = make_float4(a0.x + xo[0], a0.y + xo[1], a0.z + xo[2], a0.w + xo[3]);
            o1 = make_float4(a1.x + xo[4], a1.y + xo[5], a1.z + xo[6], a1.w + xo[7]);
        } else {
            float4 a0 = ((const float4*)(acc_out + o))[0];
            float4 a1 = ((const float4*)(acc_out + o))[1];
            o0 = make_float4((a0.x + xo[0]) * 0.25f, (a0.y + xo[1]) * 0.25f,
                             (a0.z + xo[2]) * 0.25f, (a0.w + xo[3]) * 0.25f);
            o1 = make_float4((a1.x + xo[4]) * 0.25f, (a1.y + xo[5]) * 0.25f,
                             (a1.z + xo[6]) * 0.25f, (a1.w + xo[7]) * 0.25f);
        }
        ((float4*)(acc_out + o))[0] = o0;
        ((float4*)(acc_out + o))[1] = o1;

        if (mode != 2) {
            union { ushort h[8]; uint4 u; } pk;
#pragma unroll
            for (int j = 0; j < 8; j++) {
                __hip_bfloat16 b = __float2bfloat16(xo[j] * di);
                pk.h[j] = *(ushort*)&b;
            }
            *((uint4*)(znext + o)) = pk.u;
        }
    }
}

extern "C" void kernel_launch(void* const* d_in, const int* in_sizes, int n_in,
                              void* d_out, int out_size, void* d_ws, size_t ws_size,
                              hipStream_t stream) {
    const float* emb = (const float*)d_in[0];
    const int* ei = (const int*)d_in[1];  // [2, E]: row = ei[0:E], col = ei[E:2E]
    float* out = (float*)d_out;

    char* ws = (char*)d_ws;
    size_t off = 0;
    auto alloc = [&](size_t bytes) -> void* {
        void* p = ws + off;
        off += (bytes + 511) & ~(size_t)511;
        return p;
    };
    int* deg = (int*)alloc((size_t)N_NODES * 4);
    float* dinv = (float*)alloc((size_t)N_NODES * 4);
    int* base = (int*)alloc((size_t)N_NODES * 4);
    int* cursor = (int*)alloc((size_t)N_NODES * 4);
    int* bsums = (int*)alloc(64 * 4);
    int* csrc = (int*)alloc((size_t)N_EDGES * 4);
    __hip_bfloat16* zA = (__hip_bfloat16*)alloc((size_t)N_NODES * DIM * 2);
    __hip_bfloat16* zB = (__hip_bfloat16*)alloc((size_t)N_NODES * DIM * 2);

    hipMemsetAsync(deg, 0, (size_t)N_NODES * 4, stream);

    int nBlocks = (N_NODES + 255) / 256;
    int edgeBlocks = (EDGE_VEC + 255) / 256;  // 3125

    k_count<<<edgeBlocks, 256, 0, stream>>>(ei, deg);
    k_dinv<<<nBlocks, 256, 0, stream>>>(deg, dinv);
    k_scan1<<<SCAN_NBLOCKS, SCAN_BLOCK, 0, stream>>>(deg, base, bsums);
    k_scan2<<<1, 64, 0, stream>>>(bsums, SCAN_NBLOCKS);
    k_scan3<<<nBlocks, 256, 0, stream>>>(base, bsums, cursor);
    k_fill<<<edgeBlocks, 256, 0, stream>>>(ei, cursor, csrc);
    k_z0<<<(N_NODES * DIM / 4 + 255) / 256, 256, 0, stream>>>(emb, dinv, zA);

    int spmvBlocks = (N_NODES + 3) / 4;  // 4 waves/block, 1 wave/node
    k_spmv<<<spmvBlocks, 256, 0, stream>>>(base, deg, csrc, zA, dinv, zB, emb, out, 0);
    k_spmv<<<spmvBlocks, 256, 0, stream>>>(base, deg, csrc, zB, dinv, zA, emb, out, 1);
    k_spmv<<<spmvBlocks, 256, 0, stream>>>(base, deg, csrc, zA, dinv, zB, emb, out, 2);
}

// Round 2
// 359.468 us; speedup vs baseline: 1.6749x; 1.6749x over previous
//
#include <hip/hip_runtime.h>
#include <hip/hip_bf16.h>
#include <stdint.h>

// LightGCN on MI355X, round 5.
// R4 post-mortem: agent-scope write-through csrc stores made it WORSE
// (WRITE_SIZE 166->200MB = exactly 64B/edge: every scattered dword store
// costs a full line at the memory side; nothing combines). Partial lines
// only combine while resident in ONE cache with ONE owner.
// R5: two-level bucket sort.
//   k_bucket: 391 blocks x 8192 edges; LDS-sort into 196 dst-range buckets
//     (512 nodes each, entry packed (row<<9)|dstLocal in 32 bits), flush
//     contiguous runs to bucket-segmented staging (coalesced full-line
//     writes; one cursor atomic per block x bucket).
//   k_build: 1 block per bucket; LDS per-dst count + local scan (+ tiny
//     global bucket scan) -> deg/base/dinv; scatter rows into this
//     bucket's 65KB csrc range = exclusive L2-resident owner -> lines
//     combine before eviction. Replaces count/dinv/scan1-3/fill.
// SpMV unchanged from R3/R4 (wave=dst node, 8 rows/wave-load, shfl reduce).

#define N_NODES 100000
#define N_EDGES 3200000
#define DIM 64

#define NB 196               // ceil(100000/512) dst buckets
#define BSH 9                // 512 nodes per bucket
#define BNODES 512
#define CAP 20480            // staging slots per bucket (mean 16327, sigma~128)

#define CHUNK 8192           // edges per k_bucket block
#define NBLK1 ((N_EDGES + CHUNK - 1) / CHUNK)  // 391

__device__ __forceinline__ float bl(unsigned u) { return __uint_as_float(u << 16); }
__device__ __forceinline__ float bh(unsigned u) { return __uint_as_float(u & 0xffff0000u); }

// ---- level 1: bucket edges by dst range ----
__global__ __launch_bounds__(256) void k_bucket(const int* __restrict__ ei,
                                                int* __restrict__ gcursor,
                                                int* __restrict__ staging) {
    __shared__ int stage[CHUNK];       // packed (row<<9)|dstLocal
    __shared__ int bcnt[NB];
    __shared__ int boff[NB];
    __shared__ int bstart[NB];
    __shared__ int gbase[NB];
    __shared__ int wt[4];

    int t = threadIdx.x;
    int e0 = blockIdx.x * CHUNK;
    int nblk = min(CHUNK, N_EDGES - e0);
    int nvec = nblk >> 2;

    const int4* col4 = (const int4*)(ei + N_EDGES + e0);
    const int4* row4 = (const int4*)(ei + e0);

    for (int i = t; i < NB; i += 256) { bcnt[i] = 0; boff[i] = 0; }
    __syncthreads();

    // phase A: count per bucket
    for (int i = t; i < nvec; i += 256) {
        int4 c = col4[i];
        atomicAdd(&bcnt[c.x >> BSH], 1);
        atomicAdd(&bcnt[c.y >> BSH], 1);
        atomicAdd(&bcnt[c.z >> BSH], 1);
        atomicAdd(&bcnt[c.w >> BSH], 1);
    }
    __syncthreads();

    // phase B: exclusive scan of bcnt -> bstart; reserve global runs
    {
        int v = (t < NB) ? bcnt[t] : 0;
        int lane = t & 63, w = t >> 6;
        int s = v;
#pragma unroll
        for (int off = 1; off < 64; off <<= 1) {
            int u = __shfl_up(s, off);
            if (lane >= off) s += u;
        }
        if (lane == 63) wt[w] = s;
        __syncthreads();
        int wo = 0;
        for (int ww = 0; ww < w; ww++) wo += wt[ww];
        if (t < NB) {
            bstart[t] = s - v + wo;
            gbase[t] = (v > 0) ? atomicAdd(&gcursor[t], v) : 0;
        }
    }
    __syncthreads();

    // phase C: place edges into LDS, bucket-sorted
    for (int i = t; i < nvec; i += 256) {
        int4 c = col4[i];
        int4 r = row4[i];
        int b0 = c.x >> BSH, b1 = c.y >> BSH, b2 = c.z >> BSH, b3 = c.w >> BSH;
        int p0 = bstart[b0] + atomicAdd(&boff[b0], 1);
        int p1 = bstart[b1] + atomicAdd(&boff[b1], 1);
        int p2 = bstart[b2] + atomicAdd(&boff[b2], 1);
        int p3 = bstart[b3] + atomicAdd(&boff[b3], 1);
        stage[p0] = (r.x << BSH) | (c.x & (BNODES - 1));
        stage[p1] = (r.y << BSH) | (c.y & (BNODES - 1));
        stage[p2] = (r.z << BSH) | (c.z & (BNODES - 1));
        stage[p3] = (r.w << BSH) | (c.w & (BNODES - 1));
    }
    __syncthreads();

    // phase D: flush runs contiguously (coalesced across the wave)
    for (int i = t; i < nblk; i += 256) {
        int e = stage[i];
        int b = (e & (BNODES - 1)) >> 31;  // placeholder, recompute below
        // bucket from dstLocal alone is ambiguous; find run via bstart:
        // instead recompute from stage order: we stored dstLocal only, so
        // carry bucket via binary search over bstart. Cheaper: recompute
        // bucket from position with a second LDS array? Use search:
        int lo = 0, hi = NB - 1;
        while (lo < hi) {
            int mid = (lo + hi + 1) >> 1;
            if (bstart[mid] <= i) lo = mid; else hi = mid - 1;
        }
        b = lo;
        staging[(size_t)b * CAP + gbase[b] + (i - bstart[b])] = e;
    }
}

// ---- tiny exclusive scan over bucket totals ----
__global__ void k_bstart(const int* __restrict__ gcursor, int* __restrict__ bucketStart) {
    __shared__ int wt[4];
    int t = threadIdx.x;
    int v = (t < NB) ? gcursor[t] : 0;
    int lane = t & 63, w = t >> 6;
    int s = v;
#pragma unroll
    for (int off = 1; off < 64; off <<= 1) {
        int u = __shfl_up(s, off);
        if (lane >= off) s += u;
    }
    if (lane == 63) wt[w] = s;
    __syncthreads();
    int wo = 0;
    for (int ww = 0; ww < w; ww++) wo += wt[ww];
    if (t < NB) bucketStart[t] = s - v + wo;
}

// ---- level 2: per-bucket CSR build (count + scan + scatter, one owner) ----
__global__ __launch_bounds__(256) void k_build(const int* __restrict__ gcursor,
                                               const int* __restrict__ bucketStart,
                                               const int* __restrict__ staging,
                                               int* __restrict__ deg,
                                               int* __restrict__ base,
                                               float* __restrict__ dinv,
                                               int* __restrict__ csrc) {
    __shared__ int ldeg[BNODES];
    __shared__ int lcur[BNODES];
    __shared__ int wt[4];

    int b = blockIdx.x;
    int t = threadIdx.x;
    int n0 = b << BSH;
    int nloc = min(BNODES, N_NODES - n0);
    int cnt = gcursor[b];
    const int* st = staging + (size_t)b * CAP;

    ldeg[t] = 0; ldeg[t + 256] = 0;
    __syncthreads();

    // count per dst
    for (int i = t; i < cnt; i += 256) {
        atomicAdd(&ldeg[st[i] & (BNODES - 1)], 1);
    }
    __syncthreads();

    // block scan over 512 counters (2 per thread)
    int a0 = ldeg[2 * t], a1 = ldeg[2 * t + 1];
    int s = a0 + a1;
    int lane = t & 63, w = t >> 6;
    int ss = s;
#pragma unroll
    for (int off = 1; off < 64; off <<= 1) {
        int u = __shfl_up(ss, off);
        if (lane >= off) ss += u;
    }
    if (lane == 63) wt[w] = ss;
    __syncthreads();
    int wo = 0;
    for (int ww = 0; ww < w; ww++) wo += wt[ww];
    int excl = ss - s + wo;

    int gb = bucketStart[b] + excl;
    int n = n0 + 2 * t;
    lcur[2 * t] = gb;
    lcur[2 * t + 1] = gb + a0;
    if (2 * t < nloc) {
        deg[n] = a0;
        base[n] = gb;
        dinv[n] = (a0 > 0) ? rsqrtf((float)a0) : 0.0f;
    }
    if (2 * t + 1 < nloc) {
        deg[n + 1] = a1;
        base[n + 1] = gb + a0;
        dinv[n + 1] = (a1 > 0) ? rsqrtf((float)a1) : 0.0f;
    }
    __syncthreads();

    // scatter rows into this bucket's csrc range (L2-resident, single owner)
    for (int i = t; i < cnt; i += 256) {
        int e = st[i];
        int p = atomicAdd(&lcur[e & (BNODES - 1)], 1);
        csrc[p] = e >> BSH;
    }
}

// z0 = bf16(emb * dinv[node]) ; vectorized 4 elems/thread
__global__ void k_z0(const float* __restrict__ emb, const float* __restrict__ dinv,
                     __hip_bfloat16* __restrict__ z) {
    int i = blockIdx.x * blockDim.x + threadIdx.x;  // group of 4 elements
    if (i >= (N_NODES * DIM) / 4) return;
    float di = dinv[(i * 4) >> 6];
    const float4 v = ((const float4*)emb)[i];
    union { ushort h[4]; uint2 u; } pk;
    __hip_bfloat16 b0 = __float2bfloat16(v.x * di);
    __hip_bfloat16 b1 = __float2bfloat16(v.y * di);
    __hip_bfloat16 b2 = __float2bfloat16(v.z * di);
    __hip_bfloat16 b3 = __float2bfloat16(v.w * di);
    pk.h[0] = *(ushort*)&b0; pk.h[1] = *(ushort*)&b1;
    pk.h[2] = *(ushort*)&b2; pk.h[3] = *(ushort*)&b3;
    ((uint2*)z)[i] = pk.u;
}

// ---- SpMV: one wave per dst node; 8 rows gathered per wave-load ----
// mode 0: acc = emb + xo; znext = bf16(xo*dinv)
// mode 1: acc += xo;      znext = bf16(xo*dinv)
// mode 2: acc = (acc + xo) * 0.25
__global__ __launch_bounds__(256) void k_spmv(
    const int* __restrict__ base, const int* __restrict__ deg,
    const int* __restrict__ csrc, const __hip_bfloat16* __restrict__ z,
    const float* __restrict__ dinv, __hip_bfloat16* __restrict__ znext,
    const float* __restrict__ emb, float* __restrict__ acc_out, int mode) {
    int wave = (blockIdx.x * blockDim.x + threadIdx.x) >> 6;
    int lane = threadIdx.x & 63;
    if (wave >= N_NODES) return;
    int g = lane >> 3;   // edge slot 0..7
    int l = lane & 7;    // feature chunk: features [l*8, l*8+8)

    int start = base[wave];
    int cnt = deg[wave];

    float acc[8] = {0, 0, 0, 0, 0, 0, 0, 0};

#define ACCUM(U)                                   \
    do {                                           \
        acc[0] += bl((U).x); acc[1] += bh((U).x);  \
        acc[2] += bl((U).y); acc[3] += bh((U).y);  \
        acc[4] += bl((U).z); acc[5] += bh((U).z);  \
        acc[6] += bl((U).w); acc[7] += bh((U).w);  \
    } while (0)

    int pos = 0;
    for (; pos + 32 <= cnt; pos += 32) {
        int i0 = start + pos + g;
        int s0 = csrc[i0];
        int s1 = csrc[i0 + 8];
        int s2 = csrc[i0 + 16];
        int s3 = csrc[i0 + 24];
        uint4 v0 = *((const uint4*)(z + ((size_t)s0 << 6)) + l);
        uint4 v1 = *((const uint4*)(z + ((size_t)s1 << 6)) + l);
        uint4 v2 = *((const uint4*)(z + ((size_t)s2 << 6)) + l);
        uint4 v3 = *((const uint4*)(z + ((size_t)s3 << 6)) + l);
        ACCUM(v0); ACCUM(v1); ACCUM(v2); ACCUM(v3);
    }
    for (; pos < cnt; pos += 8) {
        int idx = pos + g;
        if (idx < cnt) {
            int s = csrc[start + idx];
            uint4 v = *((const uint4*)(z + ((size_t)s << 6)) + l);
            ACCUM(v);
        }
    }
#undef ACCUM

    // reduce across the 8 edge-slot groups (lane bits 3,4,5)
#pragma unroll
    for (int j = 0; j < 8; j++) {
        acc[j] += __shfl_xor(acc[j], 8);
        acc[j] += __shfl_xor(acc[j], 16);
        acc[j] += __shfl_xor(acc[j], 32);
    }

    if (lane < 8) {  // lane == l, holds features [l*8, l*8+8)
        float di = dinv[wave];
        size_t o = (size_t)wave * DIM + lane * 8;
        float xo[8];
#pragma unroll
        for (int j = 0; j < 8; j++) xo[j] = acc[j] * di;

        float4 o0, o1;
        if (mode == 0) {
            float4 e0 = ((const float4*)(emb + o))[0];
            float4 e1 = ((const float4*)(emb + o))[1];
            o0 = make_float4(e0.x + xo[0], e0.y + xo[1], e0.z + xo[2], e0.w + xo[3]);
            o1 = make_float4(e1.x + xo[4], e1.y + xo[5], e1.z + xo[6], e1.w + xo[7]);
        } else if (mode == 1) {
            float4 a0 = ((const float4*)(acc_out + o))[0];
            float4 a1 = ((const float4*)(acc_out + o))[1];
            o0 = make_float4(a0.x + xo[0], a0.y + xo[1], a0.z + xo[2], a0.w + xo[3]);
            o1 = make_float4(a1.x + xo[4], a1.y + xo[5], a1.z + xo[6], a1.w + xo[7]);
        } else {
            float4 a0 = ((const float4*)(acc_out + o))[0];
            float4 a1 = ((const float4*)(acc_out + o))[1];
            o0 = make_float4((a0.x + xo[0]) * 0.25f, (a0.y + xo[1]) * 0.25f,
                             (a0.z + xo[2]) * 0.25f, (a0.w + xo[3]) * 0.25f);
            o1 = make_float4((a1.x + xo[4]) * 0.25f, (a1.y + xo[5]) * 0.25f,
                             (a1.z + xo[6]) * 0.25f, (a1.w + xo[7]) * 0.25f);
        }
        ((float4*)(acc_out + o))[0] = o0;
        ((float4*)(acc_out + o))[1] = o1;

        if (mode != 2) {
            union { ushort h[8]; uint4 u; } pk;
#pragma unroll
            for (int j = 0; j < 8; j++) {
                __hip_bfloat16 b = __float2bfloat16(xo[j] * di);
                pk.h[j] = *(ushort*)&b;
            }
            *((uint4*)(znext + o)) = pk.u;
        }
    }
}

extern "C" void kernel_launch(void* const* d_in, const int* in_sizes, int n_in,
                              void* d_out, int out_size, void* d_ws, size_t ws_size,
                              hipStream_t stream) {
    const float* emb = (const float*)d_in[0];
    const int* ei = (const int*)d_in[1];  // [2, E]: row = ei[0:E], col = ei[E:2E]
    float* out = (float*)d_out;

    char* ws = (char*)d_ws;
    size_t off = 0;
    auto alloc = [&](size_t bytes) -> void* {
        void* p = ws + off;
        off += (bytes + 511) & ~(size_t)511;
        return p;
    };
    // persistent region
    int* deg = (int*)alloc((size_t)N_NODES * 4);
    float* dinv = (float*)alloc((size_t)N_NODES * 4);
    int* base = (int*)alloc((size_t)N_NODES * 4);
    int* gcursor = (int*)alloc(NB * 4);
    int* bucketStart = (int*)alloc(NB * 4);
    int* csrc = (int*)alloc((size_t)N_EDGES * 4);
    // transient union: staging (16MB) is dead after k_build; overlay zA/zB
    char* transient = (char*)alloc((size_t)NB * CAP * 4);  // 16.05 MB
    int* staging = (int*)transient;
    __hip_bfloat16* zA = (__hip_bfloat16*)transient;                    // 12.8 MB
    __hip_bfloat16* zB = (__hip_bfloat16*)alloc((size_t)N_NODES * DIM * 2);

    hipMemsetAsync(gcursor, 0, NB * 4, stream);

    k_bucket<<<NBLK1, 256, 0, stream>>>(ei, gcursor, staging);
    k_bstart<<<1, 256, 0, stream>>>(gcursor, bucketStart);
    k_build<<<NB, 256, 0, stream>>>(gcursor, bucketStart, staging, deg, base, dinv, csrc);
    // staging dead from here; zA overlays it
    k_z0<<<(N_NODES * DIM / 4 + 255) / 256, 256, 0, stream>>>(emb, dinv, zA);

    int spmvBlocks = (N_NODES + 3) / 4;  // 4 waves/block, 1 wave/node
    k_spmv<<<spmvBlocks, 256, 0, stream>>>(base, deg, csrc, zA, dinv, zB, emb, out, 0);
    k_spmv<<<spmvBlocks, 256, 0, stream>>>(base, deg, csrc, zB, dinv, zA, emb, out, 1);
    k_spmv<<<spmvBlocks, 256, 0, stream>>>(base, deg, csrc, zA, dinv, zB, emb, out, 2);
}

// Round 3
// 337.654 us; speedup vs baseline: 1.7831x; 1.0646x over previous
//
#include <hip/hip_runtime.h>
#include <hip/hip_bf16.h>
#include <stdint.h>

// LightGCN on MI355X, round 6.
// R5 post-mortem: CSR build fixed (two-level bucket sort; spmv WRITE now
// exactly payload). Profile now = k_spmv x3 @67us, FETCH 175MB, 40% HBM,
// VALU 37% -> latency-bound. Cause: Poisson(32) degrees => ~47% of nodes
// run ZERO iterations of the 4-gather unrolled loop; all their edges go
// through the remainder path at one dependent gather per trip.
// R6: uniform gather loop. Every 32-edge chunk issues 4 csrc loads + 4 row
// gathers; invalid slots clamp the csrc index and redirect the source to a
// zero row at z[N_NODES] (L2-hot, adds 0.0). No divergent remainder.
// Also: k_bucket phase D bucket-id via LDS byte array (kills the 8-step
// binary search per element).

#define N_NODES 100000
#define N_EDGES 3200000
#define DIM 64

#define NB 196               // ceil(100000/512) dst buckets
#define BSH 9                // 512 nodes per bucket
#define BNODES 512
#define CAP 20480            // staging slots per bucket (mean 16327)

#define CHUNK 8192           // edges per k_bucket block
#define NBLK1 ((N_EDGES + CHUNK - 1) / CHUNK)  // 391

__device__ __forceinline__ float bl(unsigned u) { return __uint_as_float(u << 16); }
__device__ __forceinline__ float bh(unsigned u) { return __uint_as_float(u & 0xffff0000u); }

// ---- level 1: bucket edges by dst range ----
__global__ __launch_bounds__(256) void k_bucket(const int* __restrict__ ei,
                                                int* __restrict__ gcursor,
                                                int* __restrict__ staging) {
    __shared__ int stage[CHUNK];            // packed (row<<9)|dstLocal
    __shared__ unsigned char sbkt[CHUNK];   // bucket id per staged entry
    __shared__ int bcnt[NB];
    __shared__ int boff[NB];
    __shared__ int bstart[NB];
    __shared__ int gbase[NB];
    __shared__ int wt[4];

    int t = threadIdx.x;
    int e0 = blockIdx.x * CHUNK;
    int nblk = min(CHUNK, N_EDGES - e0);
    int nvec = nblk >> 2;

    const int4* col4 = (const int4*)(ei + N_EDGES + e0);
    const int4* row4 = (const int4*)(ei + e0);

    for (int i = t; i < NB; i += 256) { bcnt[i] = 0; boff[i] = 0; }
    __syncthreads();

    // phase A: count per bucket
    for (int i = t; i < nvec; i += 256) {
        int4 c = col4[i];
        atomicAdd(&bcnt[c.x >> BSH], 1);
        atomicAdd(&bcnt[c.y >> BSH], 1);
        atomicAdd(&bcnt[c.z >> BSH], 1);
        atomicAdd(&bcnt[c.w >> BSH], 1);
    }
    __syncthreads();

    // phase B: exclusive scan of bcnt -> bstart; reserve global runs
    {
        int v = (t < NB) ? bcnt[t] : 0;
        int lane = t & 63, w = t >> 6;
        int s = v;
#pragma unroll
        for (int off = 1; off < 64; off <<= 1) {
            int u = __shfl_up(s, off);
            if (lane >= off) s += u;
        }
        if (lane == 63) wt[w] = s;
        __syncthreads();
        int wo = 0;
        for (int ww = 0; ww < w; ww++) wo += wt[ww];
        if (t < NB) {
            bstart[t] = s - v + wo;
            gbase[t] = (v > 0) ? atomicAdd(&gcursor[t], v) : 0;
        }
    }
    __syncthreads();

    // phase C: place edges into LDS, bucket-sorted; remember bucket id
    for (int i = t; i < nvec; i += 256) {
        int4 c = col4[i];
        int4 r = row4[i];
        int b0 = c.x >> BSH, b1 = c.y >> BSH, b2 = c.z >> BSH, b3 = c.w >> BSH;
        int p0 = bstart[b0] + atomicAdd(&boff[b0], 1);
        int p1 = bstart[b1] + atomicAdd(&boff[b1], 1);
        int p2 = bstart[b2] + atomicAdd(&boff[b2], 1);
        int p3 = bstart[b3] + atomicAdd(&boff[b3], 1);
        stage[p0] = (r.x << BSH) | (c.x & (BNODES - 1)); sbkt[p0] = (unsigned char)b0;
        stage[p1] = (r.y << BSH) | (c.y & (BNODES - 1)); sbkt[p1] = (unsigned char)b1;
        stage[p2] = (r.z << BSH) | (c.z & (BNODES - 1)); sbkt[p2] = (unsigned char)b2;
        stage[p3] = (r.w << BSH) | (c.w & (BNODES - 1)); sbkt[p3] = (unsigned char)b3;
    }
    __syncthreads();

    // phase D: flush runs contiguously (coalesced across the wave)
    for (int i = t; i < nblk; i += 256) {
        int e = stage[i];
        int b = sbkt[i];
        staging[(size_t)b * CAP + gbase[b] + (i - bstart[b])] = e;
    }
}

// ---- tiny exclusive scan over bucket totals ----
__global__ void k_bstart(const int* __restrict__ gcursor, int* __restrict__ bucketStart) {
    __shared__ int wt[4];
    int t = threadIdx.x;
    int v = (t < NB) ? gcursor[t] : 0;
    int lane = t & 63, w = t >> 6;
    int s = v;
#pragma unroll
    for (int off = 1; off < 64; off <<= 1) {
        int u = __shfl_up(s, off);
        if (lane >= off) s += u;
    }
    if (lane == 63) wt[w] = s;
    __syncthreads();
    int wo = 0;
    for (int ww = 0; ww < w; ww++) wo += wt[ww];
    if (t < NB) bucketStart[t] = s - v + wo;
}

// ---- level 2: per-bucket CSR build (count + scan + scatter, one owner) ----
__global__ __launch_bounds__(256) void k_build(const int* __restrict__ gcursor,
                                               const int* __restrict__ bucketStart,
                                               const int* __restrict__ staging,
                                               int* __restrict__ deg,
                                               int* __restrict__ base,
                                               float* __restrict__ dinv,
                                               int* __restrict__ csrc) {
    __shared__ int ldeg[BNODES];
    __shared__ int lcur[BNODES];
    __shared__ int wt[4];

    int b = blockIdx.x;
    int t = threadIdx.x;
    int n0 = b << BSH;
    int nloc = min(BNODES, N_NODES - n0);
    int cnt = gcursor[b];
    const int* st = staging + (size_t)b * CAP;

    ldeg[t] = 0; ldeg[t + 256] = 0;
    __syncthreads();

    // count per dst
    for (int i = t; i < cnt; i += 256) {
        atomicAdd(&ldeg[st[i] & (BNODES - 1)], 1);
    }
    __syncthreads();

    // block scan over 512 counters (2 per thread)
    int a0 = ldeg[2 * t], a1 = ldeg[2 * t + 1];
    int s = a0 + a1;
    int lane = t & 63, w = t >> 6;
    int ss = s;
#pragma unroll
    for (int off = 1; off < 64; off <<= 1) {
        int u = __shfl_up(ss, off);
        if (lane >= off) ss += u;
    }
    if (lane == 63) wt[w] = ss;
    __syncthreads();
    int wo = 0;
    for (int ww = 0; ww < w; ww++) wo += wt[ww];
    int excl = ss - s + wo;

    int gb = bucketStart[b] + excl;
    int n = n0 + 2 * t;
    lcur[2 * t] = gb;
    lcur[2 * t + 1] = gb + a0;
    if (2 * t < nloc) {
        deg[n] = a0;
        base[n] = gb;
        dinv[n] = (a0 > 0) ? rsqrtf((float)a0) : 0.0f;
    }
    if (2 * t + 1 < nloc) {
        deg[n + 1] = a1;
        base[n + 1] = gb + a0;
        dinv[n + 1] = (a1 > 0) ? rsqrtf((float)a1) : 0.0f;
    }
    __syncthreads();

    // scatter rows into this bucket's csrc range (L2-resident, single owner)
    for (int i = t; i < cnt; i += 256) {
        int e = st[i];
        int p = atomicAdd(&lcur[e & (BNODES - 1)], 1);
        csrc[p] = e >> BSH;
    }
}

// z0 = bf16(emb * dinv[node]) ; vectorized 4 elems/thread
__global__ void k_z0(const float* __restrict__ emb, const float* __restrict__ dinv,
                     __hip_bfloat16* __restrict__ z) {
    int i = blockIdx.x * blockDim.x + threadIdx.x;  // group of 4 elements
    if (i >= (N_NODES * DIM) / 4) return;
    float di = dinv[(i * 4) >> 6];
    const float4 v = ((const float4*)emb)[i];
    union { ushort h[4]; uint2 u; } pk;
    __hip_bfloat16 b0 = __float2bfloat16(v.x * di);
    __hip_bfloat16 b1 = __float2bfloat16(v.y * di);
    __hip_bfloat16 b2 = __float2bfloat16(v.z * di);
    __hip_bfloat16 b3 = __float2bfloat16(v.w * di);
    pk.h[0] = *(ushort*)&b0; pk.h[1] = *(ushort*)&b1;
    pk.h[2] = *(ushort*)&b2; pk.h[3] = *(ushort*)&b3;
    ((uint2*)z)[i] = pk.u;
}

// ---- SpMV: one wave per dst node; uniform 32-edge chunks, 4 gathers in
// flight always; invalid slots redirect to the zero row z[N_NODES] ----
// mode 0: acc = emb + xo; znext = bf16(xo*dinv)
// mode 1: acc += xo;      znext = bf16(xo*dinv)
// mode 2: acc = (acc + xo) * 0.25
__global__ __launch_bounds__(256) void k_spmv(
    const int* __restrict__ base, const int* __restrict__ deg,
    const int* __restrict__ csrc, const __hip_bfloat16* __restrict__ z,
    const float* __restrict__ dinv, __hip_bfloat16* __restrict__ znext,
    const float* __restrict__ emb, float* __restrict__ acc_out, int mode) {
    int wave = (blockIdx.x * blockDim.x + threadIdx.x) >> 6;
    int lane = threadIdx.x & 63;
    if (wave >= N_NODES) return;
    int g = lane >> 3;   // edge slot 0..7
    int l = lane & 7;    // feature chunk: features [l*8, l*8+8)

    int start = base[wave];
    int cnt = deg[wave];
    int last = start + max(cnt - 1, 0);  // clamp target for csrc fetch

    float acc[8] = {0, 0, 0, 0, 0, 0, 0, 0};

#define ACCUM(U)                                   \
    do {                                           \
        acc[0] += bl((U).x); acc[1] += bh((U).x);  \
        acc[2] += bl((U).y); acc[3] += bh((U).y);  \
        acc[4] += bl((U).z); acc[5] += bh((U).z);  \
        acc[6] += bl((U).w); acc[7] += bh((U).w);  \
    } while (0)

    for (int pos = 0; pos < cnt; pos += 32) {
        int e = pos + g;
        int i0 = start + e;
        int j0 = min(i0, last);
        int j1 = min(i0 + 8, last);
        int j2 = min(i0 + 16, last);
        int j3 = min(i0 + 24, last);
        int s0 = csrc[j0];
        int s1 = csrc[j1];
        int s2 = csrc[j2];
        int s3 = csrc[j3];
        if (e >= cnt)      s0 = N_NODES;   // zero row
        if (e + 8 >= cnt)  s1 = N_NODES;
        if (e + 16 >= cnt) s2 = N_NODES;
        if (e + 24 >= cnt) s3 = N_NODES;
        uint4 v0 = *((const uint4*)(z + ((size_t)s0 << 6)) + l);
        uint4 v1 = *((const uint4*)(z + ((size_t)s1 << 6)) + l);
        uint4 v2 = *((const uint4*)(z + ((size_t)s2 << 6)) + l);
        uint4 v3 = *((const uint4*)(z + ((size_t)s3 << 6)) + l);
        ACCUM(v0); ACCUM(v1); ACCUM(v2); ACCUM(v3);
    }
#undef ACCUM

    // reduce across the 8 edge-slot groups (lane bits 3,4,5)
#pragma unroll
    for (int j = 0; j < 8; j++) {
        acc[j] += __shfl_xor(acc[j], 8);
        acc[j] += __shfl_xor(acc[j], 16);
        acc[j] += __shfl_xor(acc[j], 32);
    }

    if (lane < 8) {  // lane == l, holds features [l*8, l*8+8)
        float di = dinv[wave];
        size_t o = (size_t)wave * DIM + lane * 8;
        float xo[8];
#pragma unroll
        for (int j = 0; j < 8; j++) xo[j] = acc[j] * di;

        float4 o0, o1;
        if (mode == 0) {
            float4 e0 = ((const float4*)(emb + o))[0];
            float4 e1 = ((const float4*)(emb + o))[1];
            o0 = make_float4(e0.x + xo[0], e0.y + xo[1], e0.z + xo[2], e0.w + xo[3]);
            o1 = make_float4(e1.x + xo[4], e1.y + xo[5], e1.z + xo[6], e1.w + xo[7]);
        } else if (mode == 1) {
            float4 a0 = ((const float4*)(acc_out + o))[0];
            float4 a1 = ((const float4*)(acc_out + o))[1];
            o0 = make_float4(a0.x + xo[0], a0.y + xo[1], a0.z + xo[2], a0.w + xo[3]);
            o1 = make_float4(a1.x + xo[4], a1.y + xo[5], a1.z + xo[6], a1.w + xo[7]);
        } else {
            float4 a0 = ((const float4*)(acc_out + o))[0];
            float4 a1 = ((const float4*)(acc_out + o))[1];
            o0 = make_float4((a0.x + xo[0]) * 0.25f, (a0.y + xo[1]) * 0.25f,
                             (a0.z + xo[2]) * 0.25f, (a0.w + xo[3]) * 0.25f);
            o1 = make_float4((a1.x + xo[4]) * 0.25f, (a1.y + xo[5]) * 0.25f,
                             (a1.z + xo[6]) * 0.25f, (a1.w + xo[7]) * 0.25f);
        }
        ((float4*)(acc_out + o))[0] = o0;
        ((float4*)(acc_out + o))[1] = o1;

        if (mode != 2) {
            union { ushort h[8]; uint4 u; } pk;
#pragma unroll
            for (int j = 0; j < 8; j++) {
                __hip_bfloat16 b = __float2bfloat16(xo[j] * di);
                pk.h[j] = *(ushort*)&b;
            }
            *((uint4*)(znext + o)) = pk.u;
        }
    }
}

extern "C" void kernel_launch(void* const* d_in, const int* in_sizes, int n_in,
                              void* d_out, int out_size, void* d_ws, size_t ws_size,
                              hipStream_t stream) {
    const float* emb = (const float*)d_in[0];
    const int* ei = (const int*)d_in[1];  // [2, E]: row = ei[0:E], col = ei[E:2E]
    float* out = (float*)d_out;

    char* ws = (char*)d_ws;
    size_t off = 0;
    auto alloc = [&](size_t bytes) -> void* {
        void* p = ws + off;
        off += (bytes + 511) & ~(size_t)511;
        return p;
    };
    // persistent region
    int* deg = (int*)alloc((size_t)N_NODES * 4);
    float* dinv = (float*)alloc((size_t)N_NODES * 4);
    int* base = (int*)alloc((size_t)N_NODES * 4);
    int* gcursor = (int*)alloc(NB * 4);
    int* bucketStart = (int*)alloc(NB * 4);
    int* csrc = (int*)alloc((size_t)N_EDGES * 4);
    // transient union: staging (16MB) is dead after k_build; overlay zA
    // z buffers have N_NODES+1 rows; row N_NODES is the zero row.
    size_t zbytes = (size_t)(N_NODES + 1) * DIM * 2;  // 12.81 MB
    size_t stbytes = (size_t)NB * CAP * 4;            // 16.05 MB
    char* transient = (char*)alloc(stbytes > zbytes ? stbytes : zbytes);
    int* staging = (int*)transient;
    __hip_bfloat16* zA = (__hip_bfloat16*)transient;
    __hip_bfloat16* zB = (__hip_bfloat16*)alloc(zbytes);

    hipMemsetAsync(gcursor, 0, NB * 4, stream);

    k_bucket<<<NBLK1, 256, 0, stream>>>(ei, gcursor, staging);
    k_bstart<<<1, 256, 0, stream>>>(gcursor, bucketStart);
    k_build<<<NB, 256, 0, stream>>>(gcursor, bucketStart, staging, deg, base, dinv, csrc);
    // staging dead from here; zA overlays it
    k_z0<<<(N_NODES * DIM / 4 + 255) / 256, 256, 0, stream>>>(emb, dinv, zA);
    // zero rows at index N_NODES (gather target for invalid slots)
    hipMemsetAsync(zA + (size_t)N_NODES * DIM, 0, DIM * 2, stream);
    hipMemsetAsync(zB + (size_t)N_NODES * DIM, 0, DIM * 2, stream);

    int spmvBlocks = (N_NODES + 3) / 4;  // 4 waves/block, 1 wave/node
    k_spmv<<<spmvBlocks, 256, 0, stream>>>(base, deg, csrc, zA, dinv, zB, emb, out, 0);
    k_spmv<<<spmvBlocks, 256, 0, stream>>>(base, deg, csrc, zB, dinv, zA, emb, out, 1);
    k_spmv<<<spmvBlocks, 256, 0, stream>>>(base, deg, csrc, zA, dinv, zB, emb, out, 2);
}

// Round 4
// 324.700 us; speedup vs baseline: 1.8542x; 1.0399x over previous
//
#include <hip/hip_runtime.h>
#include <hip/hip_bf16.h>
#include <hip/hip_fp16.h>
#include <stdint.h>

// LightGCN on MI355X, round 7.
// R6 post-mortem: uniform gather loop helped (67->62us, VALU 37->52%) but
// spmv is now jointly VALU-bound (16 unpack+add ops per 8-elem gather) and
// gather-path bound; 28% of gathers are zero-row padding (chunk=32 vs
// exact ceil(deg/8)).
// R7: (1) z in fp16; accumulate via v_pk_add_f16 (4 ops per gather, 4x
// fewer; precision IMPROVES: absmax was exactly the bf16 half-ulp of z).
// (2) exact gather-group count: 4-unrolled over 8-edge groups +
// wave-uniform tail (cnt uniform per wave -> no divergence). (3) packed
// half2 shuffle reduce. (4) zero-row init folded into k_z0 spare block.
// (5) k_bucket CHUNK 4096 (782 blocks -> better CU balance).

#define N_NODES 100000
#define N_EDGES 3200000
#define DIM 64

#define NB 196               // ceil(100000/512) dst buckets
#define BSH 9                // 512 nodes per bucket
#define BNODES 512
#define CAP 20480            // staging slots per bucket (mean 16327)

#define CHUNK 4096           // edges per k_bucket block
#define NBLK1 ((N_EDGES + CHUNK - 1) / CHUNK)  // 782

// ---- level 1: bucket edges by dst range ----
__global__ __launch_bounds__(256) void k_bucket(const int* __restrict__ ei,
                                                int* __restrict__ gcursor,
                                                int* __restrict__ staging) {
    __shared__ int stage[CHUNK];            // packed (row<<9)|dstLocal
    __shared__ unsigned char sbkt[CHUNK];   // bucket id per staged entry
    __shared__ int bcnt[NB];
    __shared__ int boff[NB];
    __shared__ int bstart[NB];
    __shared__ int gbase[NB];
    __shared__ int wt[4];

    int t = threadIdx.x;
    int e0 = blockIdx.x * CHUNK;
    int nblk = min(CHUNK, N_EDGES - e0);
    int nvec = nblk >> 2;

    const int4* col4 = (const int4*)(ei + N_EDGES + e0);
    const int4* row4 = (const int4*)(ei + e0);

    for (int i = t; i < NB; i += 256) { bcnt[i] = 0; boff[i] = 0; }
    __syncthreads();

    // phase A: count per bucket
    for (int i = t; i < nvec; i += 256) {
        int4 c = col4[i];
        atomicAdd(&bcnt[c.x >> BSH], 1);
        atomicAdd(&bcnt[c.y >> BSH], 1);
        atomicAdd(&bcnt[c.z >> BSH], 1);
        atomicAdd(&bcnt[c.w >> BSH], 1);
    }
    __syncthreads();

    // phase B: exclusive scan of bcnt -> bstart; reserve global runs
    {
        int v = (t < NB) ? bcnt[t] : 0;
        int lane = t & 63, w = t >> 6;
        int s = v;
#pragma unroll
        for (int off = 1; off < 64; off <<= 1) {
            int u = __shfl_up(s, off);
            if (lane >= off) s += u;
        }
        if (lane == 63) wt[w] = s;
        __syncthreads();
        int wo = 0;
        for (int ww = 0; ww < w; ww++) wo += wt[ww];
        if (t < NB) {
            bstart[t] = s - v + wo;
            gbase[t] = (v > 0) ? atomicAdd(&gcursor[t], v) : 0;
        }
    }
    __syncthreads();

    // phase C: place edges into LDS, bucket-sorted; remember bucket id
    for (int i = t; i < nvec; i += 256) {
        int4 c = col4[i];
        int4 r = row4[i];
        int b0 = c.x >> BSH, b1 = c.y >> BSH, b2 = c.z >> BSH, b3 = c.w >> BSH;
        int p0 = bstart[b0] + atomicAdd(&boff[b0], 1);
        int p1 = bstart[b1] + atomicAdd(&boff[b1], 1);
        int p2 = bstart[b2] + atomicAdd(&boff[b2], 1);
        int p3 = bstart[b3] + atomicAdd(&boff[b3], 1);
        stage[p0] = (r.x << BSH) | (c.x & (BNODES - 1)); sbkt[p0] = (unsigned char)b0;
        stage[p1] = (r.y << BSH) | (c.y & (BNODES - 1)); sbkt[p1] = (unsigned char)b1;
        stage[p2] = (r.z << BSH) | (c.z & (BNODES - 1)); sbkt[p2] = (unsigned char)b2;
        stage[p3] = (r.w << BSH) | (c.w & (BNODES - 1)); sbkt[p3] = (unsigned char)b3;
    }
    __syncthreads();

    // phase D: flush runs contiguously (coalesced across the wave)
    for (int i = t; i < nblk; i += 256) {
        int e = stage[i];
        int b = sbkt[i];
        staging[(size_t)b * CAP + gbase[b] + (i - bstart[b])] = e;
    }
}

// ---- tiny exclusive scan over bucket totals ----
__global__ void k_bstart(const int* __restrict__ gcursor, int* __restrict__ bucketStart) {
    __shared__ int wt[4];
    int t = threadIdx.x;
    int v = (t < NB) ? gcursor[t] : 0;
    int lane = t & 63, w = t >> 6;
    int s = v;
#pragma unroll
    for (int off = 1; off < 64; off <<= 1) {
        int u = __shfl_up(s, off);
        if (lane >= off) s += u;
    }
    if (lane == 63) wt[w] = s;
    __syncthreads();
    int wo = 0;
    for (int ww = 0; ww < w; ww++) wo += wt[ww];
    if (t < NB) bucketStart[t] = s - v + wo;
}

// ---- level 2: per-bucket CSR build (count + scan + scatter, one owner) ----
__global__ __launch_bounds__(256) void k_build(const int* __restrict__ gcursor,
                                               const int* __restrict__ bucketStart,
                                               const int* __restrict__ staging,
                                               int* __restrict__ deg,
                                               int* __restrict__ base,
                                               float* __restrict__ dinv,
                                               int* __restrict__ csrc) {
    __shared__ int ldeg[BNODES];
    __shared__ int lcur[BNODES];
    __shared__ int wt[4];

    int b = blockIdx.x;
    int t = threadIdx.x;
    int n0 = b << BSH;
    int nloc = min(BNODES, N_NODES - n0);
    int cnt = gcursor[b];
    const int* st = staging + (size_t)b * CAP;

    ldeg[t] = 0; ldeg[t + 256] = 0;
    __syncthreads();

    // count per dst
    for (int i = t; i < cnt; i += 256) {
        atomicAdd(&ldeg[st[i] & (BNODES - 1)], 1);
    }
    __syncthreads();

    // block scan over 512 counters (2 per thread)
    int a0 = ldeg[2 * t], a1 = ldeg[2 * t + 1];
    int s = a0 + a1;
    int lane = t & 63, w = t >> 6;
    int ss = s;
#pragma unroll
    for (int off = 1; off < 64; off <<= 1) {
        int u = __shfl_up(ss, off);
        if (lane >= off) ss += u;
    }
    if (lane == 63) wt[w] = ss;
    __syncthreads();
    int wo = 0;
    for (int ww = 0; ww < w; ww++) wo += wt[ww];
    int excl = ss - s + wo;

    int gb = bucketStart[b] + excl;
    int n = n0 + 2 * t;
    lcur[2 * t] = gb;
    lcur[2 * t + 1] = gb + a0;
    if (2 * t < nloc) {
        deg[n] = a0;
        base[n] = gb;
        dinv[n] = (a0 > 0) ? rsqrtf((float)a0) : 0.0f;
    }
    if (2 * t + 1 < nloc) {
        deg[n + 1] = a1;
        base[n + 1] = gb + a0;
        dinv[n + 1] = (a1 > 0) ? rsqrtf((float)a1) : 0.0f;
    }
    __syncthreads();

    // scatter rows into this bucket's csrc range (L2-resident, single owner)
    for (int i = t; i < cnt; i += 256) {
        int e = st[i];
        int p = atomicAdd(&lcur[e & (BNODES - 1)], 1);
        csrc[p] = e >> BSH;
    }
}

// z0 = fp16(emb * dinv[node]); last block also zeroes the zero rows of zA/zB
__global__ void k_z0(const float* __restrict__ emb, const float* __restrict__ dinv,
                     __half* __restrict__ zA, __half* __restrict__ zB) {
    const int total = (N_NODES * DIM) / 4;  // 1.6M groups of 4
    int i = blockIdx.x * blockDim.x + threadIdx.x;
    if (i >= total) {
        int r = i - total;
        if (r < 16) ((uint2*)(zA + (size_t)N_NODES * DIM))[r] = make_uint2(0, 0);
        else if (r < 32) ((uint2*)(zB + (size_t)N_NODES * DIM))[r - 16] = make_uint2(0, 0);
        return;
    }
    float di = dinv[(i * 4) >> 6];
    const float4 v = ((const float4*)emb)[i];
    union { ushort h[4]; uint2 u; } pk;
    __half h0 = __float2half(v.x * di);
    __half h1 = __float2half(v.y * di);
    __half h2 = __float2half(v.z * di);
    __half h3 = __float2half(v.w * di);
    pk.h[0] = *(ushort*)&h0; pk.h[1] = *(ushort*)&h1;
    pk.h[2] = *(ushort*)&h2; pk.h[3] = *(ushort*)&h3;
    ((uint2*)zA)[i] = pk.u;
}

// ---- SpMV: one wave per dst node; exact ceil(deg/8) gather groups of 8
// edges; fp16 rows, packed half2 accumulate; invalid slots -> zero row ----
// mode 0: acc = emb + xo; znext = fp16(xo*dinv)
// mode 1: acc += xo;      znext = fp16(xo*dinv)
// mode 2: acc = (acc + xo) * 0.25
__global__ __launch_bounds__(256) void k_spmv(
    const int* __restrict__ base, const int* __restrict__ deg,
    const int* __restrict__ csrc, const __half* __restrict__ z,
    const float* __restrict__ dinv, __half* __restrict__ znext,
    const float* __restrict__ emb, float* __restrict__ acc_out, int mode) {
    int wave = (blockIdx.x * blockDim.x + threadIdx.x) >> 6;
    int lane = threadIdx.x & 63;
    if (wave >= N_NODES) return;
    int g = lane >> 3;   // edge slot within group 0..7
    int l = lane & 7;    // feature chunk: features [l*8, l*8+8)

    int start = base[wave];
    int cnt = deg[wave];
    float di = dinv[wave];
    int ng = (cnt + 7) >> 3;   // gather groups (wave-uniform)

    __half2 hz = __float2half2_rn(0.0f);
    __half2 hacc0 = hz, hacc1 = hz, hacc2 = hz, hacc3 = hz;

#define GLOAD(KK, SVAR)                              \
    int e##SVAR = (KK) * 8 + g;                      \
    int SVAR = csrc[start + e##SVAR];                \
    SVAR = (e##SVAR < cnt) ? SVAR : N_NODES;

#define GACC(SVAR)                                                        \
    do {                                                                  \
        uint4 v = *((const uint4*)(z + ((size_t)SVAR << 6)) + l);         \
        const __half2* hv = (const __half2*)&v;                           \
        hacc0 = __hadd2(hacc0, hv[0]);                                    \
        hacc1 = __hadd2(hacc1, hv[1]);                                    \
        hacc2 = __hadd2(hacc2, hv[2]);                                    \
        hacc3 = __hadd2(hacc3, hv[3]);                                    \
    } while (0)

    int k = 0;
    for (; k + 4 <= ng; k += 4) {
        GLOAD(k + 0, s0); GLOAD(k + 1, s1); GLOAD(k + 2, s2); GLOAD(k + 3, s3);
        GACC(s0); GACC(s1); GACC(s2); GACC(s3);
    }
    int rem = ng - k;           // wave-uniform 0..3
    if (rem > 0) {
        GLOAD(k + 0, t0);
        if (rem > 1) { GLOAD(k + 1, t1);
            if (rem > 2) { GLOAD(k + 2, t2); GACC(t0); GACC(t1); GACC(t2); }
            else { GACC(t0); GACC(t1); }
        } else { GACC(t0); }
    }
#undef GLOAD
#undef GACC

    // packed reduce across the 8 edge-slot groups (lane bits 3,4,5)
#pragma unroll
    for (int off = 8; off <= 32; off <<= 1) {
        int b0 = __shfl_xor(*(int*)&hacc0, off);
        int b1 = __shfl_xor(*(int*)&hacc1, off);
        int b2 = __shfl_xor(*(int*)&hacc2, off);
        int b3 = __shfl_xor(*(int*)&hacc3, off);
        hacc0 = __hadd2(hacc0, *(__half2*)&b0);
        hacc1 = __hadd2(hacc1, *(__half2*)&b1);
        hacc2 = __hadd2(hacc2, *(__half2*)&b2);
        hacc3 = __hadd2(hacc3, *(__half2*)&b3);
    }

    if (lane < 8) {  // lane == l, holds features [l*8, l*8+8)
        size_t o = (size_t)wave * DIM + lane * 8;
        float xo[8];
        xo[0] = __low2float(hacc0) * di; xo[1] = __high2float(hacc0) * di;
        xo[2] = __low2float(hacc1) * di; xo[3] = __high2float(hacc1) * di;
        xo[4] = __low2float(hacc2) * di; xo[5] = __high2float(hacc2) * di;
        xo[6] = __low2float(hacc3) * di; xo[7] = __high2float(hacc3) * di;

        float4 o0, o1;
        if (mode == 0) {
            float4 e0 = ((const float4*)(emb + o))[0];
            float4 e1 = ((const float4*)(emb + o))[1];
            o0 = make_float4(e0.x + xo[0], e0.y + xo[1], e0.z + xo[2], e0.w + xo[3]);
            o1 = make_float4(e1.x + xo[4], e1.y + xo[5], e1.z + xo[6], e1.w + xo[7]);
        } else if (mode == 1) {
            float4 a0 = ((const float4*)(acc_out + o))[0];
            float4 a1 = ((const float4*)(acc_out + o))[1];
            o0 = make_float4(a0.x + xo[0], a0.y + xo[1], a0.z + xo[2], a0.w + xo[3]);
            o1 = make_float4(a1.x + xo[4], a1.y + xo[5], a1.z + xo[6], a1.w + xo[7]);
        } else {
            float4 a0 = ((const float4*)(acc_out + o))[0];
            float4 a1 = ((const float4*)(acc_out + o))[1];
            o0 = make_float4((a0.x + xo[0]) * 0.25f, (a0.y + xo[1]) * 0.25f,
                             (a0.z + xo[2]) * 0.25f, (a0.w + xo[3]) * 0.25f);
            o1 = make_float4((a1.x + xo[4]) * 0.25f, (a1.y + xo[5]) * 0.25f,
                             (a1.z + xo[6]) * 0.25f, (a1.w + xo[7]) * 0.25f);
        }
        ((float4*)(acc_out + o))[0] = o0;
        ((float4*)(acc_out + o))[1] = o1;

        if (mode != 2) {
            union { ushort h[8]; uint4 u; } pk;
#pragma unroll
            for (int j = 0; j < 8; j++) {
                __half hh = __float2half(xo[j] * di);
                pk.h[j] = *(ushort*)&hh;
            }
            *((uint4*)(znext + o)) = pk.u;
        }
    }
}

extern "C" void kernel_launch(void* const* d_in, const int* in_sizes, int n_in,
                              void* d_out, int out_size, void* d_ws, size_t ws_size,
                              hipStream_t stream) {
    const float* emb = (const float*)d_in[0];
    const int* ei = (const int*)d_in[1];  // [2, E]: row = ei[0:E], col = ei[E:2E]
    float* out = (float*)d_out;

    char* ws = (char*)d_ws;
    size_t off = 0;
    auto alloc = [&](size_t bytes) -> void* {
        void* p = ws + off;
        off += (bytes + 511) & ~(size_t)511;
        return p;
    };
    // persistent region
    int* deg = (int*)alloc((size_t)N_NODES * 4);
    float* dinv = (float*)alloc((size_t)N_NODES * 4);
    int* base = (int*)alloc((size_t)N_NODES * 4);
    int* gcursor = (int*)alloc(NB * 4);
    int* bucketStart = (int*)alloc(NB * 4);
    int* csrc = (int*)alloc(((size_t)N_EDGES + 64) * 4);  // +64 overread slack
    // transient union: staging (16MB) is dead after k_build; overlay zA
    // z buffers have N_NODES+1 rows; row N_NODES is the zero row.
    size_t zbytes = (size_t)(N_NODES + 1) * DIM * 2;  // 12.81 MB
    size_t stbytes = (size_t)NB * CAP * 4;            // 16.05 MB
    char* transient = (char*)alloc(stbytes > zbytes ? stbytes : zbytes);
    int* staging = (int*)transient;
    __half* zA = (__half*)transient;
    __half* zB = (__half*)alloc(zbytes);

    hipMemsetAsync(gcursor, 0, NB * 4, stream);

    k_bucket<<<NBLK1, 256, 0, stream>>>(ei, gcursor, staging);
    k_bstart<<<1, 256, 0, stream>>>(gcursor, bucketStart);
    k_build<<<NB, 256, 0, stream>>>(gcursor, bucketStart, staging, deg, base, dinv, csrc);
    // staging dead from here; zA overlays it. Last block zeroes zero rows.
    k_z0<<<(N_NODES * DIM / 4) / 256 + 1, 256, 0, stream>>>(emb, dinv, zA, zB);

    int spmvBlocks = (N_NODES + 3) / 4;  // 4 waves/block, 1 wave/node
    k_spmv<<<spmvBlocks, 256, 0, stream>>>(base, deg, csrc, zA, dinv, zB, emb, out, 0);
    k_spmv<<<spmvBlocks, 256, 0, stream>>>(base, deg, csrc, zB, dinv, zA, emb, out, 1);
    k_spmv<<<spmvBlocks, 256, 0, stream>>>(base, deg, csrc, zA, dinv, zB, emb, out, 2);
}